// Round 2
// baseline (193.683 us; speedup 1.0000x reference)
//
#include <hip/hip_runtime.h>

// AI4Burgers: Lu = 0.5*conv3x3(u,w1) - u_vel*conv3x3(u,w2) - u_vel*conv3x3(u,w3)
// replicate pad, B=16, H=W=1024, fp32.
//
// R7/R8 (burst single-wave blocks): 62-74us, 1.8-2.4 TB/s, Occupancy 17-19%,
// wave lifetime ~14us for ~0.5us of work -> latency-serial. FETCH(66MB) ==
// WRITE(66MB) proves inputs are L3-resident: true HBM traffic ~132MB = 21us
// at copy BW. Nothing is service-bound; the burst-then-vmcnt(0) structure
// simply never gets enough waves in flight.
//
// R9: copy-ubench structure. 2048 blocks x 256 threads (4 waves); each block
// spans one full 1024-wide row band (ROWS=8), each thread owns 4 columns and
// walks the band with a rolling 3-row register window, prefetch distance 2-3.
// Per row-step: 2 overlapping unaligned float4 u-loads (halo for free, no
// scalar gathers, no shuffles) + 1 vel load + 1 store + ~100 VALU. TLP does
// the latency hiding: waves_per_eu(4,8) caps VGPR at 128 and targets >=16
// waves/CU. Plain stores (201MB working set fits 256MB L3). Bijective XCD
// chunk swizzle keeps vertically-adjacent bands (shared halo rows) on the
// same XCD L2.

#define HH 1024
#define WW 1024
#define ROWS 8                // rows per block
#define TPB 256               // 4 waves; 256 thr x 4 px = full row width

typedef float f32x4 __attribute__((ext_vector_type(4)));

__device__ __forceinline__ float rfl(float x) {
    union { float f; int i; } c; c.f = x;
    c.i = __builtin_amdgcn_readfirstlane(c.i);   // wave-uniform -> SGPR
    return c.f;
}

__global__ __attribute__((amdgpu_flat_work_group_size(TPB, TPB),
                          amdgpu_waves_per_eu(4, 8)))
void burgers_stencil(
    const float* __restrict__ u,
    const float* __restrict__ uvel,
    const float* __restrict__ w1,
    const float* __restrict__ w2,
    const float* __restrict__ w3,
    float* __restrict__ out,
    int bandsPerImg)
{
    // Bijective XCD chunk swizzle (grid % 8 == 0): contiguous band ranges
    // per XCD so vertical neighbors (shared halo rows) hit the same L2.
    int swz = blockIdx.x;
    const int nwg = gridDim.x;
    if ((nwg & 7) == 0) {
        const int chunk = nwg >> 3;
        swz = (swz & 7) * chunk + (swz >> 3);
    }
    const int band = swz % bandsPerImg;
    const int b    = swz / bandsPerImg;
    const int y0   = band * ROWS;
    const int x0   = (int)threadIdx.x * 4;

    const size_t img = (size_t)b * (HH * WW);
    const float* ub = u + img;
    const float* vb = uvel + img;
    float* ob       = out + img;

    // Weights -> SGPRs (independent s_loads).
    float W1[9], W23[9];
#pragma unroll
    for (int i = 0; i < 9; ++i) {
        W1[i]  = rfl(w1[i]);
        W23[i] = rfl(w2[i] + w3[i]);    // fold: Lu = 0.5*c1 - vel*(c2+c3)
    }

    // Halo columns via two overlapping (unaligned) float4 loads per row:
    //   a = u[row, x0-1 .. x0+2], b = u[row, x0+1 .. x0+4]
    // clamped at the image edge, fixed up with selects (replicate pad).
    const bool le = (x0 == 0);
    const bool re = (x0 + 4 >= WW);
    const int  ca = le ? 0 : x0 - 1;
    const int  cb = re ? WW - 4 : x0 + 1;

    // Rolling windows: u rows in 5 slots (prefetch distance 2),
    // vel rows in 4 slots (distance 3). Fully unrolled -> constant indices.
    float4 ua[5], ubv[5];
#pragma unroll
    for (int i = 0; i < 4; ++i) {                 // rows y0-1 .. y0+2
        int yr = y0 - 1 + i;
        yr = yr < 0 ? 0 : (yr > HH - 1 ? HH - 1 : yr);
        const float* row = ub + (size_t)yr * WW;
        ua[i]  = *(const float4*)(row + ca);
        ubv[i] = *(const float4*)(row + cb);
    }
    float4 vl[4];
#pragma unroll
    for (int i = 0; i < 3; ++i) {                 // vel rows y0 .. y0+2
        int yr = y0 + i; yr = yr > HH - 1 ? HH - 1 : yr;
        vl[i] = *(const float4*)(vb + (size_t)yr * WW + x0);
    }

#pragma unroll
    for (int r = 0; r < ROWS; ++r) {
        // ---- prefetch (distance 2-3) ----
        {
            int pf = y0 + r + 3; pf = pf > HH - 1 ? HH - 1 : pf;
            const float* prow = ub + (size_t)pf * WW;
            ua[(r + 4) % 5]  = *(const float4*)(prow + ca);
            ubv[(r + 4) % 5] = *(const float4*)(prow + cb);
            vl[(r + 3) % 4]  = *(const float4*)(vb + (size_t)pf * WW + x0);
        }

        // ---- compute row y0+r from window rows r-1, r, r+1 ----
        float p[3][6];
#pragma unroll
        for (int rr = 0; rr < 3; ++rr) {
            const float4 a  = ua[(r + rr) % 5];
            const float4 bq = ubv[(r + rr) % 5];
            p[rr][0] = a.x;
            p[rr][1] = le ? a.x : a.y;
            p[rr][2] = le ? a.y : a.z;
            p[rr][3] = le ? a.z : a.w;
            p[rr][4] = le ? a.w : (re ? bq.w : bq.z);
            p[rr][5] = bq.w;
        }
        const float4 vv = vl[r % 4];
        const float vel[4] = {vv.x, vv.y, vv.z, vv.w};

        float o[4];
#pragma unroll
        for (int j = 0; j < 4; ++j) {
            float c1 = 0.f, c23 = 0.f;
#pragma unroll
            for (int rr = 0; rr < 3; ++rr) {
#pragma unroll
                for (int k = 0; k < 3; ++k) {
                    const float a = p[rr][j + k];
                    c1  = fmaf(W1[rr*3 + k],  a, c1);
                    c23 = fmaf(W23[rr*3 + k], a, c23);
                }
            }
            o[j] = fmaf(-vel[j], c23, 0.5f * c1);
        }
        float4 ov; ov.x = o[0]; ov.y = o[1]; ov.z = o[2]; ov.w = o[3];
        *(float4*)(ob + (size_t)(y0 + r) * WW + x0) = ov;
    }
}

extern "C" void kernel_launch(void* const* d_in, const int* in_sizes, int n_in,
                              void* d_out, int out_size, void* d_ws, size_t ws_size,
                              hipStream_t stream) {
    const float* u    = (const float*)d_in[0];
    const float* uvel = (const float*)d_in[1];
    const float* w1   = (const float*)d_in[2];
    const float* w2   = (const float*)d_in[3];
    const float* w3   = (const float*)d_in[4];
    float* out        = (float*)d_out;

    const int B = in_sizes[0] / (HH * WW);      // 16
    const int bandsPerImg = HH / ROWS;          // 128
    dim3 grid(B * bandsPerImg);                 // 2048 blocks
    dim3 block(TPB);
    burgers_stencil<<<grid, block, 0, stream>>>(u, uvel, w1, w2, w3, out,
                                                bandsPerImg);
}

// Round 3
// 175.886 us; speedup vs baseline: 1.1012x; 1.1012x over previous
//
#include <hip/hip_runtime.h>

// AI4Burgers: Lu = 0.5*conv3x3(u,w1) - u_vel*conv3x3(u,w2) - u_vel*conv3x3(u,w3)
// replicate pad, B=16, H=W=1024, fp32.
//
// History: R2-R6 (LDS/barrier structures) 62-72us; R7 (this body, waves_per_eu(1,2))
// 62us / 2.4TB/s / occ 17%; R8 (shuffle halo + nt stores + (1,4)) 74us; R9
// (rolling-window TLP, 256thr) 76us with VGPR sunk to 36 -> in-flight depth
// destroyed. Diagnosis across all rounds: time tracks IN-FLIGHT BYTES PER CU,
// not occupancy. ~1.5KB/CU in flight / ~600cyc L3-hit latency ~= 2 TB/s.
// R7 has the deepest real burst (VGPR=88, ~18KB issued per wave).
//
// R10 = R7 byte-identical EXCEPT amdgpu_waves_per_eu(1,2) -> (1,4).
// R7's residency was 1.4 waves/EU (occ 17%), capped by the attr max while the
// drain phase idles the SIMD. R8 proved (1,4) with min=1 leaves the burst
// codegen untouched (VGPR stayed 88: min sets the register budget, max only
// the HW residency cap). Doubling real residency doubles in-flight bytes/CU.
// Predict: occ 17->30-38%, dispatch 62->40-50us, hbm 2.4->3.1-3.7 TB/s.
// Falsifier: occ up but dur >=58us -> admission-capped, declare roofline.

#define HH 1024
#define WW 1024
#define RPB 8                 // rows per wave
#define CPW 256               // columns per wave (64 lanes x 4 px)
#define NROW (RPB + 2)        // staged u rows (halo factor 1.25)

__device__ __forceinline__ float rfl(float x) {
    union { float f; int i; } c; c.f = x;
    c.i = __builtin_amdgcn_readfirstlane(c.i);   // wave-uniform -> SGPR
    return c.f;
}

__global__ __attribute__((amdgpu_flat_work_group_size(64, 64),
                          amdgpu_waves_per_eu(1, 4)))
void burgers_stencil(
    const float* __restrict__ u,
    const float* __restrict__ uvel,
    const float* __restrict__ w1,
    const float* __restrict__ w2,
    const float* __restrict__ w3,
    float* __restrict__ out,
    int rowBlocks, int colBlocks)
{
    const int lane = threadIdx.x;
    int rem = blockIdx.x;
    const int xb = rem % colBlocks; rem /= colBlocks;   // adjacent blocks share rows -> L2 halo hits
    const int yb = rem % rowBlocks; rem /= rowBlocks;
    const int b  = rem;

    const int y0 = yb * RPB;
    const int x0 = xb * CPW + lane * 4;

    const size_t img = (size_t)b * HH * WW;
    const float* ub  = u + img;

    // Weights -> SGPRs first (s_load, lgkmcnt, independent of the VMEM burst).
    float W1[9], W23[9];
#pragma unroll
    for (int i = 0; i < 9; ++i) {
        W1[i]  = rfl(w1[i]);
        W23[i] = rfl(w2[i] + w3[i]);    // fold: Lu = 0.5*c1 - vel*(c2+c3)
    }

    // Clamped halo columns: clamp IS the replicate pad, never OOB.
    const int xl = (x0 == 0) ? 0 : x0 - 1;
    const int xr = (x0 + 4 >= WW) ? WW - 1 : x0 + 4;

    // ---- the burst: 38 independent VMEM ops, ~18KB in flight per wave ----
    float4 uv[NROW]; float ul[NROW], ur[NROW];
#pragma unroll
    for (int i = 0; i < NROW; ++i) {
        int yr = y0 - 1 + i;
        yr = yr < 0 ? 0 : (yr > HH - 1 ? HH - 1 : yr);   // replicate pad rows
        const float* row = ub + (size_t)yr * WW;
        uv[i] = *(const float4*)(row + x0);
        ul[i] = row[xl];
        ur[i] = row[xr];
    }
    float4 vv[RPB];
#pragma unroll
    for (int r = 0; r < RPB; ++r)
        vv[r] = *(const float4*)(uvel + img + (size_t)(y0 + r) * WW + x0);

    __builtin_amdgcn_sched_barrier(0);  // burst stays above the math

    // ---- compute + store ----
#pragma unroll
    for (int r = 0; r < RPB; ++r) {
        float p[3][6];
#pragma unroll
        for (int rr = 0; rr < 3; ++rr) {
            const int i = r + rr;
            p[rr][0] = ul[i];
            p[rr][1] = uv[i].x; p[rr][2] = uv[i].y;
            p[rr][3] = uv[i].z; p[rr][4] = uv[i].w;
            p[rr][5] = ur[i];
        }
        const float vel[4] = {vv[r].x, vv[r].y, vv[r].z, vv[r].w};

        float o[4];
#pragma unroll
        for (int j = 0; j < 4; ++j) {
            float c1 = 0.f, c23 = 0.f;
#pragma unroll
            for (int rr = 0; rr < 3; ++rr) {
#pragma unroll
                for (int k = 0; k < 3; ++k) {
                    const float a = p[rr][j + k];
                    c1  = fmaf(W1[rr*3 + k],  a, c1);
                    c23 = fmaf(W23[rr*3 + k], a, c23);
                }
            }
            o[j] = fmaf(-vel[j], c23, 0.5f * c1);
        }
        float4 ov; ov.x = o[0]; ov.y = o[1]; ov.z = o[2]; ov.w = o[3];
        *(float4*)(out + img + (size_t)(y0 + r) * WW + x0) = ov;
    }
}

extern "C" void kernel_launch(void* const* d_in, const int* in_sizes, int n_in,
                              void* d_out, int out_size, void* d_ws, size_t ws_size,
                              hipStream_t stream) {
    const float* u    = (const float*)d_in[0];
    const float* uvel = (const float*)d_in[1];
    const float* w1   = (const float*)d_in[2];
    const float* w2   = (const float*)d_in[3];
    const float* w3   = (const float*)d_in[4];
    float* out        = (float*)d_out;

    const int B = in_sizes[0] / (HH * WW);      // 16
    const int rowBlocks = HH / RPB;             // 128
    const int colBlocks = WW / CPW;             // 4
    dim3 grid(B * rowBlocks * colBlocks);       // 8192 single-wave blocks
    dim3 block(64);
    burgers_stencil<<<grid, block, 0, stream>>>(u, uvel, w1, w2, w3, out,
                                                rowBlocks, colBlocks);
}